// Round 7
// baseline (744.678 us; speedup 1.0000x reference)
//
#include <hip/hip_runtime.h>

// Sinkhorn, fused, barrier-free dataflow loop — round 5 kernel (3rd submit;
// r5/r6 benches both failed with GPUAcquisitionTimeout, never measured).
//   k_build: KT = exp(-20*C)^T (fp32) + zero 101 iterate slots + flags.
//   k_loop : persistent, 128 blocks x 512 thr. Each wave owns TWO adjacent
//            rows and TWO adjacent cols of K in VGPRs (128 regs). Half-step t
//            writes its output into fresh pre-zeroed slot V[t+1]; iterates are
//            strictly positive, so consumers poll the data itself (relaxed
//            agent-scope loads, 0 = not ready) with s_sleep backoff.
//   Pad recurrence is BLOCK-LOCAL: P[t+1]=f(sum(V[t]),P[t]) computed
//   redundantly by every wave from its staged LDS copy (bit-identical fp64
//   sequence everywhere) -> zero pad communication, one fewer IF hop.
// Recurrence (bit-identical math to prior rounds, absmax ~7.6e-6):
//   V[0]=1, P[0]=1;  step t: out_i = (1/4096)/(sum_j K._ij V[t]_j + 2048*P[t])
//   P[t+1] = (1/4096)/(sum(V[t]) + 2048*P[t]);  K. = K (t even) / K^T (t odd)
//   w=V[99], wpad=P[99], z=V[100], zpad=P[100].

#define INV_N (1.0 / 4096.0)
#define NBLK 128

// ---- scratch layout inside d_out (67,108,864 bytes) ----
#define OFF_KT 0UL            // KT fp32 2048x2048 (out rows 0..1023)
#define OFF_V 16777216UL      // V[t] = OFF_V + t*16384, t=0..100 (out rows 1024..1125)
#define OFF_FLAGS 67096640UL  // 128 u32 epilogue flags, 32B stride (row-4095 spare)

static __device__ __forceinline__ double aload(const double* p) {
  return __hip_atomic_load(p, __ATOMIC_RELAXED, __HIP_MEMORY_SCOPE_AGENT);
}
static __device__ __forceinline__ void astore(double* p, double v) {
  __hip_atomic_store(p, v, __ATOMIC_RELAXED, __HIP_MEMORY_SCOPE_AGENT);
}

// fp64 exp (rel err ~3e-13 on [-20,0]).
static __device__ __forceinline__ double fexp(double x) {
  double t = x * 1.4426950408889634074;
  double n = rint(t);
  double r = fma(n, -0.69314718055994530942, x);
  double p = 2.7557319223985890653e-7;
  p = fma(p, r, 2.7557319223985890653e-6);
  p = fma(p, r, 2.4801587301587301587e-5);
  p = fma(p, r, 1.9841269841269841270e-4);
  p = fma(p, r, 1.3888888888888888889e-3);
  p = fma(p, r, 8.3333333333333333333e-3);
  p = fma(p, r, 4.1666666666666666667e-2);
  p = fma(p, r, 1.6666666666666666667e-1);
  p = fma(p, r, 0.5);
  p = fma(p, r, 1.0);
  p = fma(p, r, 1.0);
  long long bits = ((long long)(1023 + (int)n)) << 52;
  return p * __longlong_as_double(bits);
}

// Build KT (fp32, LDS tile transpose) + init slots/flags.
// 1024 blocks x 256 thr; one 64x64 tile per block.
__global__ __launch_bounds__(256) void k_build(const float* __restrict__ C, char* base) {
  float* KT = (float*)(base + OFF_KT);
  __shared__ float s_t[64][65];
  int b = blockIdx.x, tid = threadIdx.x;
  int ti = b >> 5, tj = b & 31;
  int r0 = tid >> 6, c = tid & 63;
#pragma unroll
  for (int k = 0; k < 16; ++k) {
    int r = r0 + 4 * k;
    int row = ti * 64 + r, col = tj * 64 + c;
    s_t[r][c] = (float)fexp(-20.0 * (double)C[(size_t)row * 2048 + col]);
  }
  __syncthreads();
#pragma unroll
  for (int k = 0; k < 16; ++k) {
    int r = r0 + 4 * k;
    KT[(size_t)(tj * 64 + r) * 2048 + ti * 64 + c] = s_t[c][r];
  }
  // slot init: block t (t<=100) owns V[t]; V[0]=1, rest 0 (not-ready sentinel).
  if (b <= 100) {
    double* Vt = (double*)(base + OFF_V) + (size_t)b * 2048;
    double val = (b == 0) ? 1.0 : 0.0;
    for (int t = tid; t < 2048; t += 256) Vt[t] = val;
  }
  if (b == 101 && tid < NBLK) ((unsigned*)(base + OFF_FLAGS))[tid * 8] = 0u;
}

// One half-step: 2 adjacent rows per wave (ka=row i0, kb=row i0+1; fp32 pairs,
// element j = 2*(l+64k)+{0,1}). Polls V[t] into sv, MACs, stores V[t+1][i0..i0+1].
// pcur = P[t] on entry, P[t+1] on exit (block-local, bit-identical everywhere).
static __device__ __forceinline__ void half_step(
    const float2 (&ka)[16], const float2 (&kb)[16], int t, char* base, double* sv,
    double& pcur, int tid, int l, int i0) {
  double* V = (double*)(base + OFF_V);
  const double* vin = V + (size_t)t * 2048;
  double* vout = V + (size_t)(t + 1) * 2048;

  double v0 = aload(vin + tid), v1 = aload(vin + tid + 512);
  double v2 = aload(vin + tid + 1024), v3 = aload(vin + tid + 1536);
  while (v0 == 0.0) { __builtin_amdgcn_s_sleep(1); v0 = aload(vin + tid); }
  while (v1 == 0.0) { __builtin_amdgcn_s_sleep(1); v1 = aload(vin + tid + 512); }
  while (v2 == 0.0) { __builtin_amdgcn_s_sleep(1); v2 = aload(vin + tid + 1024); }
  while (v3 == 0.0) { __builtin_amdgcn_s_sleep(1); v3 = aload(vin + tid + 1536); }
  sv[tid] = v0; sv[tid + 512] = v1; sv[tid + 1024] = v2; sv[tid + 1536] = v3;
  __syncthreads();
  const double2* vz = (const double2*)sv;
  double a0 = 0, a1 = 0, b0 = 0, b1 = 0, ts = 0;
#pragma unroll
  for (int k = 0; k < 16; ++k) {
    double2 p = vz[l + 64 * k];  // dense 16B/lane, conflict-free
    a0 = fma((double)ka[k].x, p.x, a0);
    a1 = fma((double)ka[k].y, p.y, a1);
    b0 = fma((double)kb[k].x, p.x, b0);
    b1 = fma((double)kb[k].y, p.y, b1);
    ts += p.x + p.y;
  }
  double accA = a0 + a1, accB = b0 + b1;
#pragma unroll
  for (int off = 32; off; off >>= 1) {
    accA += __shfl_xor(accA, off, 64);
    accB += __shfl_xor(accB, off, 64);
    ts += __shfl_xor(ts, off, 64);
  }
  double wiA = INV_N / (accA + 2048.0 * pcur);
  double wiB = INV_N / (accB + 2048.0 * pcur);
  if (l == 0) {  // adjacent pair: one 16B line segment, merges in the WC buffer
    astore(vout + i0, wiA);
    astore(vout + i0 + 1, wiB);
  }
  pcur = INV_N / (ts + 2048.0 * pcur);
  // no trailing __syncthreads: sv is double-buffered by the caller
}

// Persistent kernel: reg-load -> 100 dataflow half-steps -> epilogue.
__global__ __launch_bounds__(512, 2) void k_loop(const float* __restrict__ C, char* base) {
  const float* KT = (const float*)(base + OFF_KT);
  float* out = (float*)base;

  __shared__ double s_v[2][2048];
  __shared__ float s_valf[2048];
  __shared__ double s_w16[16];

  const int tid = threadIdx.x, b = blockIdx.x;
  const int wv = tid >> 6, l = tid & 63;
  const int i0 = b * 16 + 2 * wv;  // this wave's adjacent row pair

  // ---- pin K rows i0,i0+1 (from C, fp64 exp -> fp32) and cols i0,i0+1 (from KT) ----
  float2 kra[16], krb[16], kca[16], kcb[16];
  {
    const float2* cA = (const float2*)(C + (size_t)i0 * 2048);
    const float2* cB = (const float2*)(C + (size_t)(i0 + 1) * 2048);
    const float2* tA = (const float2*)(KT + (size_t)i0 * 2048);
    const float2* tB = (const float2*)(KT + (size_t)(i0 + 1) * 2048);
#pragma unroll
    for (int k = 0; k < 16; ++k) {
      float2 ca = cA[l + 64 * k], cb = cB[l + 64 * k];
      kra[k].x = (float)fexp(-20.0 * (double)ca.x);
      kra[k].y = (float)fexp(-20.0 * (double)ca.y);
      krb[k].x = (float)fexp(-20.0 * (double)cb.x);
      krb[k].y = (float)fexp(-20.0 * (double)cb.y);
      kca[k] = tA[l + 64 * k];
      kcb[k] = tB[l + 64 * k];
    }
  }

  double pcur = 1.0, wpad = 0.0;
  for (int t2 = 0; t2 < 50; ++t2) {
    half_step(kra, krb, 2 * t2, base, s_v[0], pcur, tid, l, i0);      // row: w from z
    wpad = pcur;  // after final row step this is P[99] = wpad
    half_step(kca, kcb, 2 * t2 + 1, base, s_v[1], pcur, tid, l, i0);  // col: z from w
  }
  double zpad = pcur;  // P[100]

  // ---- epilogue ----
  {
    const double* zf = (const double*)(base + OFF_V) + 100 * 2048;
    const double* wf = (const double*)(base + OFF_V) + 99 * 2048;
    double* sv = s_v[0];
    double v0 = aload(zf + tid), v1 = aload(zf + tid + 512);
    double v2 = aload(zf + tid + 1024), v3 = aload(zf + tid + 1536);
    while (v0 == 0.0) { __builtin_amdgcn_s_sleep(1); v0 = aload(zf + tid); }
    while (v1 == 0.0) { __builtin_amdgcn_s_sleep(1); v1 = aload(zf + tid + 512); }
    while (v2 == 0.0) { __builtin_amdgcn_s_sleep(1); v2 = aload(zf + tid + 1024); }
    while (v3 == 0.0) { __builtin_amdgcn_s_sleep(1); v3 = aload(zf + tid + 1536); }
    sv[tid] = v0; sv[tid + 512] = v1; sv[tid + 1024] = v2; sv[tid + 1536] = v3;
    if (tid < 16) {
      double x = aload(wf + b * 16 + tid);
      while (x == 0.0) { __builtin_amdgcn_s_sleep(1); x = aload(wf + b * 16 + tid); }
      s_w16[tid] = x;
    }
    // bottom-row pattern (identical for every row 2048..4095)
    s_valf[tid] = (float)(4096.0 * fmin(wpad * v0, 1.0));
    s_valf[tid + 512] = (float)(4096.0 * fmin(wpad * v1, 1.0));
    s_valf[tid + 1024] = (float)(4096.0 * fmin(wpad * v2, 1.0));
    s_valf[tid + 1536] = (float)(4096.0 * fmin(wpad * v3, 1.0));
    __syncthreads();  // all slot reads of this block complete

    // One-time device barrier: no block overwrites the slot/flag regions until
    // every block finished reading them. Late stale polls of the flag region
    // read positive output-float bit patterns (nonzero) -> no deadlock.
    unsigned* flags = (unsigned*)(base + OFF_FLAGS);
    if (tid == 0) {
      asm volatile("s_waitcnt vmcnt(0)" ::: "memory");
      __hip_atomic_store(flags + b * 8, 1u, __ATOMIC_RELAXED, __HIP_MEMORY_SCOPE_AGENT);
    }
    if (tid < 64) {  // wave 0 polls all 128 flags, 2 per lane
      for (;;) {
        unsigned x0 = __hip_atomic_load(flags + tid * 8, __ATOMIC_RELAXED, __HIP_MEMORY_SCOPE_AGENT);
        unsigned x1 = __hip_atomic_load(flags + (tid + 64) * 8, __ATOMIC_RELAXED, __HIP_MEMORY_SCOPE_AGENT);
        if (__all(x0 != 0u && x1 != 0u)) break;
        __builtin_amdgcn_s_sleep(1);
      }
    }
    __syncthreads();

    const double2* vz = (const double2*)sv;
    float cf = (float)(4096.0 * fmin(wpad * zpad, 1.0));
    float4 fcb; fcb.x = cf; fcb.y = cf; fcb.z = cf; fcb.w = cf;

#pragma unroll
    for (int rr = 0; rr < 2; ++rr) {
      const int i = i0 + rr;
      double wi = s_w16[2 * wv + rr];
      // top row i: left = 4096*min(w_i z_j exp(-20C_ij),1), right = const
      const float2* crow = (const float2*)(C + (size_t)i * 2048);
      float* orow = out + (size_t)i * 4096;
      float2* orow2 = (float2*)orow;
#pragma unroll 4
      for (int k = 0; k < 16; ++k) {
        float2 cv = crow[l + 64 * k];
        double2 pz = vz[l + 64 * k];
        float2 f;
        f.x = (float)(4096.0 * fmin(wi * pz.x * fexp(-20.0 * (double)cv.x), 1.0));
        f.y = (float)(4096.0 * fmin(wi * pz.y * fexp(-20.0 * (double)cv.y), 1.0));
        orow2[l + 64 * k] = f;
      }
      float cr = (float)(4096.0 * fmin(wi * zpad, 1.0));
      float4 fct; fct.x = cr; fct.y = cr; fct.z = cr; fct.w = cr;
#pragma unroll
      for (int k = 0; k < 8; ++k) ((float4*)(orow + 2048))[l + 64 * k] = fct;
      // bottom row 2048+i
      float* brow = out + (size_t)(2048 + i) * 4096;
#pragma unroll
      for (int k = 0; k < 8; ++k) ((float4*)brow)[l + 64 * k] = ((const float4*)s_valf)[l + 64 * k];
#pragma unroll
      for (int k = 0; k < 8; ++k) ((float4*)(brow + 2048))[l + 64 * k] = fcb;
    }
  }
}

extern "C" void kernel_launch(void* const* d_in, const int* in_sizes, int n_in,
                              void* d_out, int out_size, void* d_ws, size_t ws_size,
                              hipStream_t stream) {
  (void)in_sizes; (void)n_in; (void)out_size; (void)d_ws; (void)ws_size;
  const float* C = (const float*)d_in[0];
  char* base = (char*)d_out;
  k_build<<<1024, 256, 0, stream>>>(C, base);
  k_loop<<<NBLK, 512, 0, stream>>>(C, base);
}